// Round 1
// 714.454 us; speedup vs baseline: 1.2005x; 1.2005x over previous
//
#include <hip/hip_runtime.h>
#include <math.h>

// ---------------------------------------------------------------------------
// TransFusion3: B=2, C1=512, H1=W1=96, C2=256, H2=W2=192, D=256, NH=8, hd=32,
// WQ=24x24, WK=12x12. 64 windows per image; q-window i aligns with k-window i.
// ---------------------------------------------------------------------------

#define HW1 9216L      // 96*96
#define HW2 36864L     // 192*192
#define M1  18432L     // 2*96*96
#define M2  73728L     // 2*192*192

typedef __attribute__((ext_vector_type(8))) short short8;
typedef __attribute__((ext_vector_type(4))) float f32x4;
typedef unsigned short u16;

__device__ __forceinline__ short f2bf(float f)
{
    unsigned u = __builtin_bit_cast(unsigned, f);
    u = (u + 0x7fff + ((u >> 16) & 1)) >> 16;   // RNE
    return (short)u;
}
__device__ __forceinline__ float bf2f(u16 u)
{
    unsigned x = ((unsigned)u) << 16;
    return __builtin_bit_cast(float, x);
}
__device__ __forceinline__ float gelu_exact(float v)
{
    return 0.5f * v * (1.0f + erff(v * 0.70710678118654752f));
}

// ---------------------------------------------------------------------------
// gemm_at: C[m][n] = sum_k A(k,m)*B[k][n] + bias[n]; A fp32 K-major (NCHW),
// outputs 256-wide; split-N at 256 (blocks with n0>=256 use B2/b2/C2).
// BM=128, BN=128, BK=32; mfma 16x16x32 bf16; TC=float or u16 (LDS repack).
// ---------------------------------------------------------------------------
template<typename TC>
__global__ __launch_bounds__(256) void gemm_at(
    const float* __restrict__ A,
    const float* __restrict__ B1, const float* __restrict__ b1, TC* __restrict__ C1,
    const float* __restrict__ B2, const float* __restrict__ b2, TC* __restrict__ C2,
    int K, int ldA, int hwA, long batA)
{
    __shared__ short pool[17408];          // As[128][40] Bs[128][40] | ob[128][136]
    short* As = pool;
    short* Bs = pool + 128 * 40;
    const int tid = threadIdx.x;
    const int m0 = blockIdx.y * 128;
    int n0 = blockIdx.x * 128;
    const float* Bm; const float* bias; TC* C;
    if (n0 < 256) { Bm = B1; bias = b1; C = C1; }
    else          { Bm = B2; bias = b2; C = C2; n0 -= 256; }
    const long aBase = (long)(m0 / hwA) * batA + (long)(m0 % hwA);

    const int w = tid >> 6, lane = tid & 63;
    const int wm = (w & 1) * 64, wn = (w >> 1) * 64;
    const int lm = lane & 15, lq = lane >> 4;

    f32x4 acc[4][4] = {};

    for (int k0 = 0; k0 < K; k0 += 32) {
        {   // stage A: 128 m x 32 k
            int ml = tid & 127, kh = tid >> 7;         // kh in {0,1}: 16 k's
            const float* Ap = A + aBase + ml + (long)(k0 + kh * 16) * ldA;
            float v[16];
#pragma unroll
            for (int j = 0; j < 16; ++j) v[j] = Ap[(long)j * ldA];
            short8 s0, s1;
#pragma unroll
            for (int j = 0; j < 8; ++j) { s0[j] = f2bf(v[j]); s1[j] = f2bf(v[j + 8]); }
            *(short8*)&As[ml * 40 + kh * 16]     = s0;
            *(short8*)&As[ml * 40 + kh * 16 + 8] = s1;
        }
        {   // stage B: 128 n x 32 k (weights row-major [K][256])
            int nl = tid & 127, kc = tid >> 7;         // kc in {0,1}: 16 k's
            const float* Bp = Bm + (long)(k0 + kc * 16) * 256 + n0 + nl;
            short8 s0, s1;
#pragma unroll
            for (int j = 0; j < 8; ++j) {
                s0[j] = f2bf(Bp[(long)j * 256]);
                s1[j] = f2bf(Bp[(long)(j + 8) * 256]);
            }
            *(short8*)&Bs[nl * 40 + kc * 16]     = s0;
            *(short8*)&Bs[nl * 40 + kc * 16 + 8] = s1;
        }
        __syncthreads();
        short8 af[4], bfr[4];
#pragma unroll
        for (int r = 0; r < 4; ++r) af[r] = *(short8*)&As[(wm + r * 16 + lm) * 40 + lq * 8];
#pragma unroll
        for (int c = 0; c < 4; ++c) bfr[c] = *(short8*)&Bs[(wn + c * 16 + lm) * 40 + lq * 8];
#pragma unroll
        for (int r = 0; r < 4; ++r)
#pragma unroll
            for (int c = 0; c < 4; ++c)
                acc[r][c] = __builtin_amdgcn_mfma_f32_16x16x32_bf16(af[r], bfr[c], acc[r][c], 0, 0, 0);
        __syncthreads();
    }

    if constexpr (sizeof(TC) == 4) {
#pragma unroll
        for (int r = 0; r < 4; ++r)
#pragma unroll
            for (int i = 0; i < 4; ++i) {
                long row = (long)(m0 + wm + r * 16 + lq * 4 + i) * 256;
#pragma unroll
                for (int c = 0; c < 4; ++c) {
                    int col = n0 + wn + c * 16 + lm;
                    ((float*)C)[row + col] = acc[r][c][i] + bias[col];
                }
            }
    } else {
        short* ob = pool;   // [128][136]
#pragma unroll
        for (int r = 0; r < 4; ++r)
#pragma unroll
            for (int i = 0; i < 4; ++i) {
                int row = wm + r * 16 + lq * 4 + i;
#pragma unroll
                for (int c = 0; c < 4; ++c) {
                    int jl = wn + c * 16 + lm;
                    ob[row * 136 + jl] = f2bf(acc[r][c][i] + bias[n0 + jl]);
                }
            }
        __syncthreads();
        int m = tid >> 1, half = (tid & 1) * 64;
        u16* Cp = (u16*)C + (long)(m0 + m) * 256 + n0 + half;
#pragma unroll
        for (int q = 0; q < 8; ++q)
            *(short8*)(Cp + q * 8) = *(short8*)&ob[m * 136 + half + q * 8];
    }
}

// ---------------------------------------------------------------------------
// gemm_bf16rm: A bf16 row-major [M][ldA], B fp32 [K][N]. BM=128,BN=128,BK=64.
// EPI: 0 none, 1 exact gelu. bf16 output via LDS repack.
// ---------------------------------------------------------------------------
template<int EPI>
__global__ __launch_bounds__(256) void gemm_bf16rm(
    const u16* __restrict__ A, const float* __restrict__ Bm,
    const float* __restrict__ bias, u16* __restrict__ C,
    int N, int K, int ldA)
{
    __shared__ short pool[18432];  // As[128][72] Bs[128][72] | ob[128][136]
    short* As = pool;
    short* Bs = pool + 128 * 72;
    const int tid = threadIdx.x;
    const int m0 = blockIdx.y * 128;
    const int n0 = blockIdx.x * 128;
    const int w = tid >> 6, lane = tid & 63;
    const int wm = (w & 1) * 64, wn = (w >> 1) * 64;
    const int lm = lane & 15, lq = lane >> 4;

    f32x4 acc[4][4] = {};

    for (int k0 = 0; k0 < K; k0 += 64) {
        {   // stage A: 128 rows x 64 k, straight bf16 copy
            int m = tid >> 1, kh = (tid & 1) * 32;
            const u16* Ap = A + (long)(m0 + m) * ldA + k0 + kh;
#pragma unroll
            for (int q = 0; q < 4; ++q)
                *(short8*)&As[m * 72 + kh + q * 8] = *(const short8*)(Ap + q * 8);
        }
        {   // stage B: 128 n x 64 k
            int nl = tid & 127, kc = (tid >> 7) * 32;
            const float* Bp = Bm + (long)(k0 + kc) * N + n0 + nl;
#pragma unroll
            for (int jc = 0; jc < 4; ++jc) {
                short8 s;
#pragma unroll
                for (int j = 0; j < 8; ++j) s[j] = f2bf(Bp[(long)(jc * 8 + j) * N]);
                *(short8*)&Bs[nl * 72 + kc + jc * 8] = s;
            }
        }
        __syncthreads();
#pragma unroll
        for (int kk = 0; kk < 64; kk += 32) {
            short8 af[4], bfr[4];
#pragma unroll
            for (int r = 0; r < 4; ++r) af[r] = *(short8*)&As[(wm + r * 16 + lm) * 72 + kk + lq * 8];
#pragma unroll
            for (int c = 0; c < 4; ++c) bfr[c] = *(short8*)&Bs[(wn + c * 16 + lm) * 72 + kk + lq * 8];
#pragma unroll
            for (int r = 0; r < 4; ++r)
#pragma unroll
                for (int c = 0; c < 4; ++c)
                    acc[r][c] = __builtin_amdgcn_mfma_f32_16x16x32_bf16(af[r], bfr[c], acc[r][c], 0, 0, 0);
        }
        __syncthreads();
    }

    short* ob = pool;   // [128][136]
#pragma unroll
    for (int r = 0; r < 4; ++r)
#pragma unroll
        for (int i = 0; i < 4; ++i) {
            int row = wm + r * 16 + lq * 4 + i;
#pragma unroll
            for (int c = 0; c < 4; ++c) {
                int jl = wn + c * 16 + lm;
                float v = acc[r][c][i] + bias[n0 + jl];
                if (EPI == 1) v = gelu_exact(v);
                ob[row * 136 + jl] = f2bf(v);
            }
        }
    __syncthreads();
    int m = tid >> 1, half = (tid & 1) * 64;
    u16* Cp = C + (long)(m0 + m) * N + n0 + half;
#pragma unroll
    for (int q = 0; q < 8; ++q)
        *(short8*)(Cp + q * 8) = *(short8*)&ob[m * 136 + half + q * 8];
}

// ---------------------------------------------------------------------------
// x2t: coalesced NCHW fp32 -> NHWC(pixel-major) bf16 transpose of x2, with the
// pooled-q window sums folded in (replaces pool_q2). One block = 1 image row x
// 64 channels. LDS transpose uses an XOR swizzle (word = pix*32 +
// (c_half ^ ((pix>>2)&7)*4)) so the vector read-out side is conflict-free.
// grid 1536 = b*768 + cg*192 + h.
// ---------------------------------------------------------------------------
__global__ __launch_bounds__(256) void x2t(
    const float* __restrict__ x2, u16* __restrict__ x2pm, float* __restrict__ qg)
{
    __shared__ short T[12288];        // 192 pix x 32 words (64 ch bf16), swizzled
    __shared__ float qsum[64][8];
    const int blk = blockIdx.x;
    const int b = blk / 768, rem = blk % 768;
    const int cg = rem / 192, h = rem % 192;
    const int t = threadIdx.x;

    ((float2*)qsum)[t] = float2{0.f, 0.f};
    __syncthreads();

    const float* src = x2 + ((long)(b * 256 + cg * 64) * 192 + h) * 192;
#pragma unroll
    for (int k = 0; k < 12; ++k) {
        int idx = t + k * 256;                 // < 3072
        int c = idx / 48, col4 = idx % 48;
        float4 v = *(const float4*)(src + (long)c * HW2 + col4 * 4);
        atomicAdd(&qsum[c][col4 / 6], v.x + v.y + v.z + v.w);
        int chh = c >> 1, cb = c & 1;
        const float* vf = (const float*)&v;
#pragma unroll
        for (int j = 0; j < 4; ++j) {
            int pix = col4 * 4 + j;
            int word = pix * 32 + (chh ^ (((pix >> 2) & 7) << 2));
            T[word * 2 + cb] = f2bf(vf[j]);
        }
    }
    __syncthreads();

    u16* dst = x2pm + ((long)b * HW2 + (long)h * 192) * 256 + cg * 64;
#pragma unroll
    for (int k = 0; k < 6; ++k) {
        int idx = t + k * 256;                 // < 1536
        int pix = idx >> 3, j = idx & 7;
        int w0 = pix * 32 + ((j * 4) ^ (((pix >> 2) & 7) << 2));
        *(short8*)(dst + (long)pix * 256 + j * 8) = *(short8*)&T[w0 * 2];
    }

    // pooled-q finalize: 512 cells, 2 per thread; 24 row-blocks per window row
    {
        int wy = h / 24;
#pragma unroll
        for (int u = 0; u < 2; ++u) {
            int cell = t * 2 + u;
            int c = cell >> 3, wx = cell & 7;
            atomicAdd(qg + (long)(b * 64 + wy * 8 + wx) * 256 + cg * 64 + c,
                      qsum[c][wx] * (1.0f / 576.0f));
        }
    }
}

// ---------------------------------------------------------------------------
// qwt: q_w fp32 [K=256][N=256] -> bf16 transposed qwbT[N][K] (one-off, 128 KB)
// ---------------------------------------------------------------------------
__global__ __launch_bounds__(256) void qwt(
    const float* __restrict__ qw, u16* __restrict__ qwbT)
{
    const int k0 = blockIdx.x * 16, t = threadIdx.x;
    short s[16];
#pragma unroll
    for (int kk = 0; kk < 16; ++kk) s[kk] = f2bf(qw[(long)(k0 + kk) * 256 + t]);
    *(short8*)(qwbT + (long)t * 256 + k0)     = *(short8*)&s[0];
    *(short8*)(qwbT + (long)t * 256 + k0 + 8) = *(short8*)&s[8];
}

// ---------------------------------------------------------------------------
// wattn_ln2: fused  hln = LN( x2 + (x2@q_w + q_b)@KtV + up(og) ) -> bf16.
// Block = one 2-row window strip (48 px) x 256 ch. grid(1536).
// Phase 1: MFMA fragments read straight from global (x2pm strip + L2-hot
//          qwbT) -- no LDS, no barriers in the K loop.
// Phase 2: per-head 48x32 @ 32x32 MFMA, B-frags from L2-hot ktvb (bf16).
// qs LDS [48][288] (XOR-swizzled) only redistributes q within a wave and
// carries the pre-LN values; each wave owns ch range [w*64,w*64+64) in every
// phase, so the only cross-wave hazard is before phase 3b -> 1 barrier total.
// ---------------------------------------------------------------------------
__global__ __launch_bounds__(256) void wattn_ln2(
    const u16* __restrict__ x2pm, const u16* __restrict__ qwbT,
    const float* __restrict__ qbias, const u16* __restrict__ ktvb,
    const float* __restrict__ og, u16* __restrict__ hln,
    const float* __restrict__ n1g, const float* __restrict__ n1b)
{
    __shared__ short qs[48 * 288];           // 27648 B -> ~5 blocks/CU

    const int t = threadIdx.x;
    const int blk = blockIdx.x;              // win*12 + strip
    const int strip = blk % 12, win = blk / 12;
    const int b = win >> 6, wy = (win >> 3) & 7, wxw = win & 7;
    const int hh0 = wy * 24 + strip * 2;
    const int w = t >> 6, lane = t & 63;
    const int lm = lane & 15, lq = lane >> 4;

    // per-lane pixel base addresses (A-fragment rows p = r*16+lm)
    long pbase[3];
#pragma unroll
    for (int r = 0; r < 3; ++r) {
        int p = r * 16 + lm;
        pbase[r] = ((long)b * HW2 + (long)(hh0 + p / 24) * 192 + wxw * 24 + (p % 24)) * 256;
    }

    // ---- phase 1: q = x2 @ q_w, fragments straight from global ----
    f32x4 acc[3][4] = {};
#pragma unroll 2
    for (int kc = 0; kc < 8; ++kc) {
        const int ko = kc * 32 + lq * 8;
        short8 af[3], bfr[4];
#pragma unroll
        for (int r = 0; r < 3; ++r)
            af[r] = *(const short8*)(x2pm + pbase[r] + ko);
#pragma unroll
        for (int c = 0; c < 4; ++c)
            bfr[c] = *(const short8*)(qwbT + (long)(w * 64 + c * 16 + lm) * 256 + ko);
#pragma unroll
        for (int r = 0; r < 3; ++r)
#pragma unroll
            for (int c = 0; c < 4; ++c)
                acc[r][c] = __builtin_amdgcn_mfma_f32_16x16x32_bf16(af[r], bfr[c], acc[r][c], 0, 0, 0);
    }

    // ---- q (+bias) -> qs bf16 (XOR-swizzled rows; same-wave consumer) ----
#pragma unroll
    for (int c = 0; c < 4; ++c) {
        float bv = qbias[w * 64 + c * 16 + lm];
#pragma unroll
        for (int r = 0; r < 3; ++r)
#pragma unroll
            for (int i = 0; i < 4; ++i) {
                int row = r * 16 + lq * 4 + i;
                int col = w * 64 + c * 16 + lm;
                qs[row * 288 + (col ^ (((row >> 2) & 3) << 3))] = f2bf(acc[r][c][i] + bv);
            }
    }
    // no barrier: phase 2 reads only this wave's column range; LDS ops of one
    // wave are program-ordered (compiler inserts the lgkmcnt).

    // ---- phase 2: o = q @ KtV per head (wave w -> heads 2w, 2w+1) ----
    f32x4 oacc[2][3][2] = {};
#pragma unroll
    for (int hl = 0; hl < 2; ++hl) {
        int h = w * 2 + hl;
        short8 af2[3], bfr2[2];
#pragma unroll
        for (int r = 0; r < 3; ++r) {
            int row = r * 16 + lm;
            af2[r] = *(short8*)&qs[row * 288 + ((h * 32 + lq * 8) ^ (((row >> 2) & 3) << 3))];
        }
#pragma unroll
        for (int c = 0; c < 2; ++c)
            bfr2[c] = *(const short8*)(ktvb + ((long)(win * 8 + h) * 32 + c * 16 + lm) * 32 + lq * 8);
#pragma unroll
        for (int r = 0; r < 3; ++r)
#pragma unroll
            for (int c = 0; c < 2; ++c)
                oacc[hl][r][c] = __builtin_amdgcn_mfma_f32_16x16x32_bf16(af2[r], bfr2[c], oacc[hl][r][c], 0, 0, 0);
    }

    // ---- phase 3a: x = residual + o + up(og) -> back into qs (bf16) ----
    const float* ogb0 = og + (long)b * 64 * 256;
#pragma unroll
    for (int r = 0; r < 3; ++r)
#pragma unroll
        for (int i = 0; i < 4; ++i) {
            int p = r * 16 + lq * 4 + i;
            int hh = hh0 + (p / 24), ww = wxw * 24 + (p % 24);
            float fy = hh * (7.0f / 191.0f);
            int y0 = (int)fy; int y1 = min(y0 + 1, 7); float wyf = fy - y0;
            float fx = ww * (7.0f / 191.0f);
            int x0 = (int)fx; int x1 = min(x0 + 1, 7); float wxf = fx - x0;
            float w00 = (1.f - wyf) * (1.f - wxf), w01 = (1.f - wyf) * wxf;
            float w10 = wyf * (1.f - wxf),         w11 = wyf * wxf;
            const float* o00 = ogb0 + (y0 * 8 + x0) * 256;
            const float* o01 = ogb0 + (y0 * 8 + x1) * 256;
            const float* o10 = ogb0 + (y1 * 8 + x0) * 256;
            const float* o11 = ogb0 + (y1 * 8 + x1) * 256;
            long pix = (long)b * HW2 + (long)hh * 192 + ww;
            int swz = ((p >> 2) & 3) << 3;
#pragma unroll
            for (int hl = 0; hl < 2; ++hl) {
                int h = w * 2 + hl;
#pragma unroll
                for (int c = 0; c < 2; ++c) {
                    int ch = h * 32 + c * 16 + lm;
                    float ogv = w00 * o00[ch] + w01 * o01[ch] + w10 * o10[ch] + w11 * o11[ch];
                    float x = bf2f(x2pm[pix * 256 + ch]) + oacc[hl][r][c][i] + ogv;
                    qs[p * 288 + (ch ^ swz)] = f2bf(x);
                }
            }
        }
    __syncthreads();

    // ---- phase 3b: LN over 256 ch per pixel; wave w handles 12 px ----
    float4 g4 = *(const float4*)(n1g + lane * 4);
    float4 b4 = *(const float4*)(n1b + lane * 4);
#pragma unroll
    for (int pp = 0; pp < 12; ++pp) {
        int p = w * 12 + pp;
        int swz = ((p >> 2) & 3) << 3;
        ushort4 u4 = *(ushort4*)&qs[p * 288 + ((lane * 4) ^ swz)];
        float x0 = bf2f(u4.x), x1 = bf2f(u4.y), x2v = bf2f(u4.z), x3 = bf2f(u4.w);
        float s  = x0 + x1 + x2v + x3;
        float s2 = x0 * x0 + x1 * x1 + x2v * x2v + x3 * x3;
#pragma unroll
        for (int o = 32; o > 0; o >>= 1) {
            s  += __shfl_xor(s,  o, 64);
            s2 += __shfl_xor(s2, o, 64);
        }
        float mean = s * (1.0f / 256.0f);
        float var  = s2 * (1.0f / 256.0f) - mean * mean;
        float rs   = rsqrtf(var + 1e-5f);
        long m = (long)b * HW2 + (long)(hh0 + p / 24) * 192 + wxw * 24 + (p % 24);
        ushort4 o4;
        o4.x = (u16)f2bf((x0 - mean) * rs * g4.x + b4.x);
        o4.y = (u16)f2bf((x1 - mean) * rs * g4.y + b4.y);
        o4.z = (u16)f2bf((x2v - mean) * rs * g4.z + b4.z);
        o4.w = (u16)f2bf((x3 - mean) * rs * g4.w + b4.w);
        *(ushort4*)(hln + m * 256 + lane * 4) = o4;
    }
}

// ---------------------------------------------------------------------------
// LN over rows of 256 (fp32 in), bf16 out.
// ---------------------------------------------------------------------------
__global__ __launch_bounds__(256) void ln_sc(
    const float* __restrict__ in, u16* __restrict__ out,
    const float* __restrict__ g, const float* __restrict__ b)
{
    __shared__ float sb[4];
    long m = blockIdx.x;
    int t = threadIdx.x;
    float x = in[m * 256 + t];
    float v = x;
#pragma unroll
    for (int o = 32; o > 0; o >>= 1) v += __shfl_down(v, o, 64);
    int wv = t >> 6;
    if ((t & 63) == 0) sb[wv] = v;
    __syncthreads();
    float mean = (sb[0] + sb[1] + sb[2] + sb[3]) * (1.0f / 256.0f);
    __syncthreads();
    float d = x - mean;
    float v2 = d * d;
#pragma unroll
    for (int o = 32; o > 0; o >>= 1) v2 += __shfl_down(v2, o, 64);
    if ((t & 63) == 0) sb[wv] = v2;
    __syncthreads();
    float var = (sb[0] + sb[1] + sb[2] + sb[3]) * (1.0f / 256.0f);
    out[m * 256 + t] = (u16)f2bf(d * rsqrtf(var + 1e-5f) * g[t] + b[t]);
}

// ---------------------------------------------------------------------------
// ktv_kernel: per (window, head) K^T V; now emits bf16 in [n][k] layout so
// wattn_ln2 can read B-fragments directly from L2.
// ---------------------------------------------------------------------------
__global__ __launch_bounds__(256) void ktv_kernel(
    const u16* __restrict__ kb, const u16* __restrict__ vb,
    u16* __restrict__ ktvb)
{
    int blk = blockIdx.x;          // win*8 + head
    int win = blk >> 3, hd = blk & 7;
    int b = win >> 6, wy = (win >> 3) & 7, wx = win & 7;
    __shared__ float ks[144][33];
    __shared__ float vs[144][33];
    int t = threadIdx.x;
#pragma unroll
    for (int it = 0; it < 18; ++it) {
        int idx = t + it * 256;
        int p = idx >> 5, c = idx & 31;
        int py = p / 12, px = p % 12;
        long m = (long)b * HW1 + (long)(wy * 12 + py) * 96 + wx * 12 + px;
        ks[p][c] = bf2f(kb[m * 256 + hd * 32 + c]);
        vs[p][c] = bf2f(vb[m * 256 + hd * 32 + c]);
    }
    __syncthreads();
    int i = t >> 3, j0 = (t & 7) * 4;
    float acc[4] = {0.f, 0.f, 0.f, 0.f};
    for (int p = 0; p < 144; ++p) {
        float kv = ks[p][i];
#pragma unroll
        for (int jj = 0; jj < 4; ++jj) acc[jj] += kv * vs[p][j0 + jj];
    }
    long ob = (long)blk * 32 * 32;
#pragma unroll
    for (int jj = 0; jj < 4; ++jj)
        ktvb[ob + (j0 + jj) * 32 + i] = (u16)f2bf(acc[jj]);   // [n][k]
}

// ---------------------------------------------------------------------------
__device__ __forceinline__ float pe4(int t, float e)
{
    if (t == 0) return sinf(e);
    if (t == 1) return cosf(e);
    if (t == 2) return sinf(e * 0.01f);
    return cosf(e * 0.01f);
}

// ---------------------------------------------------------------------------
// pool_k2c: coalesced pooled-k (replaces scatter pool_k2). One block = one
// (b,c) plane of x1; float4 row reads -> LDS row-window partials -> store.
// grid 1024 = b*512 + c. No global atomics, no memset needed for kg.
// ---------------------------------------------------------------------------
__global__ __launch_bounds__(256) void pool_k2c(
    const float* __restrict__ x1, float* __restrict__ kg)
{
    __shared__ float rw[96][8];
    int blk = blockIdx.x;
    int b = blk >> 9, c = blk & 511;
    int t = threadIdx.x;
    if (t < 192) ((float4*)rw)[t] = float4{0.f, 0.f, 0.f, 0.f};
    __syncthreads();
    const float* plane = x1 + (long)blk * HW1;
#pragma unroll
    for (int k = 0; k < 9; ++k) {
        int idx = t + k * 256;           // < 2304
        int row = idx / 24, col4 = idx % 24;
        float4 v = *(const float4*)(plane + row * 96 + col4 * 4);
        atomicAdd(&rw[row][col4 / 3], v.x + v.y + v.z + v.w);
    }
    __syncthreads();
    if (t < 64) {
        int wy = t >> 3, wx = t & 7;
        float s = 0.f;
#pragma unroll
        for (int r = 0; r < 12; ++r) s += rw[wy * 12 + r][wx];
        kg[(long)(b * 64 + wy * 8 + wx) * 512 + c] = s * (1.0f / 144.0f);
    }
}

// add sine-pos (reference's permuted-shape call) to pooled qg/kg. grid 128.
__global__ __launch_bounds__(256) void posfix(
    float* __restrict__ qg, float* __restrict__ kg)
{
    int win = blockIdx.x;
    int gy = (win >> 3) & 7, gx = win & 7;
    int t = threadIdx.x;
    const float TWO_PI = 6.283185307179586f;
    {
        float pos;
        if (gy < 4) pos = pe4(gy,     (gx + 1) * (TWO_PI / (8.0f + 1e-5f)));
        else        pos = pe4(gy - 4, (t + 1)  * (TWO_PI / (256.0f + 1e-5f)));
        qg[(long)win * 256 + t] += pos;
    }
#pragma unroll
    for (int h = 0; h < 2; ++h) {
        int c = t + h * 256;
        float pos;
        if (gy < 4) pos = pe4(gy,     (gx + 1) * (TWO_PI / (8.0f + 1e-5f)));
        else        pos = pe4(gy - 4, (c + 1)  * (TWO_PI / (512.0f + 1e-5f)));
        kg[(long)win * 512 + c] += pos;
    }
}

// ---------------------------------------------------------------------------
template<int EPI>
__global__ __launch_bounds__(256) void gemm64(
    const float* __restrict__ A, const float* __restrict__ Bm,
    const float* __restrict__ bias, float* __restrict__ C,
    int N, int K, int ldA)
{
    constexpr int BK = 16;
    __shared__ float As[BK][68];
    __shared__ float Bs[BK][68];
    const int tid = threadIdx.x;
    const int m0 = blockIdx.y * 64;
    const int n0 = blockIdx.x * 64;
    const int tm = (tid >> 4) << 2;
    const int tn = (tid & 15) << 2;
    float acc[4][4] = {};
    for (int k0 = 0; k0 < K; k0 += BK) {
#pragma unroll
        for (int it = 0; it < 4; ++it) {
            int idx = tid + it * 256;
            int my = idx >> 4, kx = idx & 15;
            As[kx][my] = A[(long)(m0 + my) * ldA + (k0 + kx)];
        }
#pragma unroll
        for (int it = 0; it < 4; ++it) {
            int idx = tid + it * 256;
            int ky = idx >> 6, nx = idx & 63;
            Bs[ky][nx] = Bm[(long)(k0 + ky) * N + (n0 + nx)];
        }
        __syncthreads();
#pragma unroll
        for (int kk = 0; kk < BK; ++kk) {
            float a[4], b[4];
#pragma unroll
            for (int i = 0; i < 4; ++i) a[i] = As[kk][tm + i];
#pragma unroll
            for (int j = 0; j < 4; ++j) b[j] = Bs[kk][tn + j];
#pragma unroll
            for (int i = 0; i < 4; ++i)
#pragma unroll
                for (int j = 0; j < 4; ++j) acc[i][j] += a[i] * b[j];
        }
        __syncthreads();
    }
#pragma unroll
    for (int i = 0; i < 4; ++i) {
        long row = (long)(m0 + tm + i) * N;
#pragma unroll
        for (int j = 0; j < 4; ++j) {
            float v = acc[i][j] + bias[n0 + tn + j];
            if (EPI == 1) v = gelu_exact(v);
            C[row + n0 + tn + j] = v;
        }
    }
}

// ---------------------------------------------------------------------------
__global__ __launch_bounds__(256) void gattn(
    const float* __restrict__ qg2, const float* __restrict__ kg2,
    const float* __restrict__ vg, float* __restrict__ og)
{
    __shared__ float qh[64][33], kh[64][33], vh[64][33];
    __shared__ float S[64][65];
    __shared__ float rinv[64];
    int blk = blockIdx.x;
    int b = blk >> 3, hd = blk & 7;
    int t = threadIdx.x;
#pragma unroll
    for (int it = 0; it < 8; ++it) {
        int idx = t + it * 256;
        int n = idx >> 5, i = idx & 31;
        long src = (long)(b * 64 + n) * 256 + hd * 32 + i;
        qh[n][i] = qg2[src];
        kh[n][i] = kg2[src];
        vh[n][i] = vg[src];
    }
    __syncthreads();
    int r = t >> 2, c0 = (t & 3) * 16;
    for (int c = c0; c < c0 + 16; ++c) {
        float s = 0.f;
#pragma unroll
        for (int i = 0; i < 32; ++i) s += qh[r][i] * kh[c][i];
        S[r][c] = s;
    }
    __syncthreads();
    if (t < 64) {
        float mx = -1e30f;
        for (int c = 0; c < 64; ++c) mx = fmaxf(mx, S[t][c]);
        float sm = 0.f;
        for (int c = 0; c < 64; ++c) {
            float e = expf(S[t][c] - mx);
            S[t][c] = e;
            sm += e;
        }
        rinv[t] = 1.0f / sm;
    }
    __syncthreads();
    int n = t >> 2, j0 = (t & 3) * 8;
    float inv = rinv[n];
    for (int j = j0; j < j0 + 8; ++j) {
        float s = 0.f;
        for (int c = 0; c < 64; ++c) s += S[n][c] * vh[c][j];
        og[(long)(b * 64 + n) * 256 + hd * 32 + j] = s * inv;
    }
}

// ---------------------------------------------------------------------------
// out = LN(mlp + bilinear_ac(sc, 96->192)) -> NCHW fp32. bf16 inputs.
// ---------------------------------------------------------------------------
__global__ __launch_bounds__(256) void final_k3(
    const u16* __restrict__ mlp, const u16* __restrict__ sc,
    const float* __restrict__ g, const float* __restrict__ bb,
    float* __restrict__ out)
{
    __shared__ float lnb[32][258];
    int blk = blockIdx.x;              // b*1152 + hh*6 + strip
    int b = blk / 1152;
    int rem = blk - b * 1152;
    int hh = rem / 6, ww0 = (rem % 6) * 32;
    int wv = threadIdx.x >> 6, lane = threadIdx.x & 63;
    int c0 = lane * 4;
    float4 g4 = *(const float4*)(g + c0);
    float4 b4 = *(const float4*)(bb + c0);
    float fy = hh * (95.0f / 191.0f);
    int y0 = (int)fy; int y1 = min(y0 + 1, 95); float wy = fy - y0;
    const u16* scb = sc + (long)b * 9216 * 256 + c0;
#pragma unroll
    for (int i = 0; i < 8; ++i) {
        int p = wv * 8 + i;
        int ww = ww0 + p;
        float fx = ww * (95.0f / 191.0f);
        int x0 = (int)fx; int x1 = min(x0 + 1, 95); float wx = fx - x0;
        ushort4 u00 = *(const ushort4*)(scb + (long)(y0 * 96 + x0) * 256);
        ushort4 u01 = *(const ushort4*)(scb + (long)(y0 * 96 + x1) * 256);
        ushort4 u10 = *(const ushort4*)(scb + (long)(y1 * 96 + x0) * 256);
        ushort4 u11 = *(const ushort4*)(scb + (long)(y1 * 96 + x1) * 256);
        long m = ((long)b * 192 + hh) * 192 + ww;
        ushort4 um = *(const ushort4*)(mlp + m * 256 + c0);
        float w00 = (1.f - wy) * (1.f - wx), w01 = (1.f - wy) * wx;
        float w10 = wy * (1.f - wx),         w11 = wy * wx;
        float xv0 = bf2f(um.x) + w00 * bf2f(u00.x) + w01 * bf2f(u01.x) + w10 * bf2f(u10.x) + w11 * bf2f(u11.x);
        float xv1 = bf2f(um.y) + w00 * bf2f(u00.y) + w01 * bf2f(u01.y) + w10 * bf2f(u10.y) + w11 * bf2f(u11.y);
        float xv2 = bf2f(um.z) + w00 * bf2f(u00.z) + w01 * bf2f(u01.z) + w10 * bf2f(u10.z) + w11 * bf2f(u11.z);
        float xv3 = bf2f(um.w) + w00 * bf2f(u00.w) + w01 * bf2f(u01.w) + w10 * bf2f(u10.w) + w11 * bf2f(u11.w);
        float s  = xv0 + xv1 + xv2 + xv3;
        float s2 = xv0 * xv0 + xv1 * xv1 + xv2 * xv2 + xv3 * xv3;
#pragma unroll
        for (int o = 32; o > 0; o >>= 1) {
            s  += __shfl_xor(s,  o, 64);
            s2 += __shfl_xor(s2, o, 64);
        }
        float mean = s * (1.0f / 256.0f);
        float var  = s2 * (1.0f / 256.0f) - mean * mean;
        float rs   = rsqrtf(var + 1e-5f);
        lnb[p][c0 + 0] = (xv0 - mean) * rs * g4.x + b4.x;
        lnb[p][c0 + 1] = (xv1 - mean) * rs * g4.y + b4.y;
        lnb[p][c0 + 2] = (xv2 - mean) * rs * g4.z + b4.z;
        lnb[p][c0 + 3] = (xv3 - mean) * rs * g4.w + b4.w;
    }
    __syncthreads();
    int tw = threadIdx.x & 31, cg = threadIdx.x >> 5;
#pragma unroll
    for (int cc = 0; cc < 32; ++cc) {
        int c = cg * 32 + cc;
        out[((long)(b * 256 + c) * 192 + hh) * 192 + ww0 + tw] = lnb[tw][c];
    }
}

// ---------------------------------------------------------------------------
extern "C" void kernel_launch(void* const* d_in, const int* in_sizes, int n_in,
                              void* d_out, int out_size, void* d_ws, size_t ws_size,
                              hipStream_t stream)
{
    const float* x1     = (const float*)d_in[0];
    const float* x2     = (const float*)d_in[1];
    const float* q_w    = (const float*)d_in[2];
    const float* q_b    = (const float*)d_in[3];
    const float* k_w    = (const float*)d_in[4];
    const float* k_b    = (const float*)d_in[5];
    const float* v_w    = (const float*)d_in[6];
    const float* v_b    = (const float*)d_in[7];
    const float* q2_w   = (const float*)d_in[8];
    const float* q2_b   = (const float*)d_in[9];
    const float* k2_w   = (const float*)d_in[10];
    const float* k2_b   = (const float*)d_in[11];
    const float* v2_w   = (const float*)d_in[12];
    const float* v2_b   = (const float*)d_in[13];
    const float* proj_w = (const float*)d_in[14];
    const float* proj_b = (const float*)d_in[15];
    const float* proj_g = (const float*)d_in[16];
    const float* proj_bt= (const float*)d_in[17];
    const float* n1_g   = (const float*)d_in[18];
    const float* n1_b   = (const float*)d_in[19];
    const float* n2_g   = (const float*)d_in[20];
    const float* n2_b   = (const float*)d_in[21];
    const float* fc1_w  = (const float*)d_in[22];
    const float* fc1_b  = (const float*)d_in[23];
    const float* fc2_w  = (const float*)d_in[24];
    const float* fc2_b  = (const float*)d_in[25];
    float* out = (float*)d_out;

    // workspace carve (bytes) -- identical footprint to the previous version
    char* p = (char*)d_ws;
    float* scf  = (float*)p;  p += M1 * 256 * 4;        // 18.9 MB proj raw
    u16*   scb  = (u16*)p;    p += M1 * 256 * 2;        //  9.4 MB sc bf16
    u16*   ktvb = (u16*)p;                              //  2.1 MB ktv bf16 [n][k]
    u16*   qwbT = (u16*)(p + 1024L * 32 * 32 * 2);      //  128 KB q_w bf16 [n][k]
    p += 1024L * 32 * 32 * 4;                           //  (slot kept at 4.2 MB)
    u16*   kb16 = (u16*)p;    p += M1 * 256 * 2;        //  9.4 MB
    u16*   vb16 = (u16*)p;    p += M1 * 256 * 2;        //  9.4 MB
    u16*   hln  = (u16*)p;    p += M2 * 256 * 2;        // 37.7 MB
    u16*   h1c  = (u16*)p;    p += 18432L * 512 * 2;    // 18.9 MB
    u16*   mlpb = (u16*)p;    p += M2 * 256 * 2;        // 37.7 MB
    float* qg   = (float*)p;  p += 128L * 256 * 4;
    float* kg   = (float*)p;  p += 128L * 512 * 4;
    float* qg2  = (float*)p;  p += 128L * 256 * 4;
    float* kg2  = (float*)p;  p += 128L * 256 * 4;
    float* vgb  = (float*)p;  p += 128L * 256 * 4;
    float* ogb  = (float*)p;  p += 128L * 256 * 4;

    // x2pm (pixel-major bf16 x2) aliases mlpb: x2pm lives [x2t .. wattn_ln2],
    // mlpb lives [MLP gemms .. final_k3] -- disjoint on the stream.
    u16* x2pm = mlpb;

    dim3 blk(256);

    // 0) zero pooled-q accumulator (kg is now fully written by pool_k2c)
    hipMemsetAsync(qg, 0, 128L * 256 * 4, stream);

    // 1) coalesced x2 transpose -> pixel-major bf16 (+ pooled-q fold-in)
    x2t<<<dim3(1536), blk, 0, stream>>>(x2, x2pm, qg);
    qwt<<<dim3(16), blk, 0, stream>>>(q_w, qwbT);

    // 2) proj GEMM -> fp32, then LN -> bf16 sc
    gemm_at<float><<<dim3(2, 144), blk, 0, stream>>>(
        x1, proj_w, proj_b, scf, proj_w, proj_b, scf, 512, 9216, 9216, 512L * 9216);
    ln_sc<<<dim3(18432), blk, 0, stream>>>(scf, scb, proj_g, proj_bt);

    // 3) k & v projections fused (split-N), bf16 out
    gemm_at<u16><<<dim3(4, 144), blk, 0, stream>>>(
        x1, k_w, k_b, kb16, v_w, v_b, vb16, 512, 9216, 9216, 512L * 9216);

    // 4) per (window, head) K^T V -> bf16 [n][k]
    ktv_kernel<<<dim3(1024), blk, 0, stream>>>(kb16, vb16, ktvb);

    // 5) coalesced pooled k, then pos add
    pool_k2c<<<dim3(1024), blk, 0, stream>>>(x1, kg);
    posfix<<<dim3(128), blk, 0, stream>>>(qg, kg);

    // 6-8) global projections (tiny, fp32) + global softmax attention
    gemm64<0><<<dim3(4, 2), blk, 0, stream>>>(qg, q2_w, q2_b, qg2, 256, 256, 256);
    gemm64<0><<<dim3(4, 2), blk, 0, stream>>>(kg, k2_w, k2_b, kg2, 256, 512, 512);
    gemm64<0><<<dim3(4, 2), blk, 0, stream>>>(kg, v2_w, v2_b, vgb, 256, 512, 512);
    gattn<<<dim3(16), blk, 0, stream>>>(qg2, kg2, vgb, ogb);

    // 9) fused q-proj + window attn + residual + og upsample + LN1
    wattn_ln2<<<dim3(1536), blk, 0, stream>>>(x2pm, qwbT, q_b, ktvb, ogb, hln, n1_g, n1_b);

    // 10-11) MLP, chunked x4 over rows; all-bf16 A operands (reuses x2pm as mlpb)
    for (int c4 = 0; c4 < 4; ++c4) {
        const u16* aoff = hln  + (long)c4 * 18432 * 256;
        u16*       coff = mlpb + (long)c4 * 18432 * 256;
        gemm_bf16rm<1><<<dim3(4, 144), blk, 0, stream>>>(
            aoff, fc1_w, fc1_b, h1c, 512, 256, 256);
        gemm_bf16rm<0><<<dim3(2, 144), blk, 0, stream>>>(
            h1c, fc2_w, fc2_b, coff, 256, 512, 512);
    }

    // 12) out = LN(mlp + upsample(sc)) -> NCHW
    final_k3<<<dim3(2304), blk, 0, stream>>>(mlpb, scb, n2_g, n2_b, out);
}